// Round 1
// baseline (754.022 us; speedup 1.0000x reference)
//
#include <hip/hip_runtime.h>
#include <hip/hip_fp16.h>

#define SQ   4096
#define DIMM 2048
#define QKVN 4096   // 2048 q | 1024 k | 1024 v

typedef unsigned short u16;
typedef unsigned int u32;
typedef __attribute__((ext_vector_type(8))) short    short8;  // bf16x8 frag
typedef __attribute__((ext_vector_type(8))) _Float16 half8;   // f16x8 frag
typedef __attribute__((ext_vector_type(4))) float    f32x4;

__device__ __forceinline__ u16 f2bf(float f) {
  u32 u = __float_as_uint(f);
  u32 r = u + 0x7fffu + ((u >> 16) & 1u);
  return (u16)(r >> 16);
}
__device__ __forceinline__ float bf2f(u16 h) { return __uint_as_float(((u32)h) << 16); }
__device__ __forceinline__ u16 f2h(float f) { return __half_as_ushort(__float2half(f)); }

__device__ __forceinline__ void gll16(const void* g, void* l) {
  __builtin_amdgcn_global_load_lds((const __attribute__((address_space(1))) void*)g,
                                   (__attribute__((address_space(3))) void*)l, 16, 0, 0);
}

// ---------------- RoPE tables (double-accurate, rounded to fp32) ----------------
__global__ __launch_bounds__(256) void k_tables(float* __restrict__ cosb, float* __restrict__ sinb) {
  int idx = blockIdx.x * 256 + threadIdx.x;  // SQ*64
  int pos = idx >> 6, i = idx & 63;
  double f = 1.0 / pow(10000.0, (double)i / 64.0);
  float inv = (float)f;
  float ang = (float)pos * inv;               // fp32 rounding matches reference table build
  cosb[idx] = (float)cos((double)ang);
  sinb[idx] = (float)sin((double)ang);
}

// ---------------- split x into bf16 hi/lo ----------------
__global__ __launch_bounds__(256) void k_split_x(const float* __restrict__ x,
                                                 u16* __restrict__ xh, u16* __restrict__ xl) {
  size_t base = ((size_t)blockIdx.x * 256 + threadIdx.x) * 4;
  float4 v = *(const float4*)(x + base);
  float vv[4] = {v.x, v.y, v.z, v.w};
  u16 hh[4], ll[4];
#pragma unroll
  for (int j = 0; j < 4; j++) {
    hh[j] = f2bf(vv[j]);
    ll[j] = f2bf(vv[j] - bf2f(hh[j]));
  }
  *(uint2*)(xh + base) = make_uint2((u32)hh[0] | ((u32)hh[1] << 16), (u32)hh[2] | ((u32)hh[3] << 16));
  *(uint2*)(xl + base) = make_uint2((u32)ll[0] | ((u32)ll[1] << 16), (u32)ll[2] | ((u32)ll[3] << 16));
}

// ---------------- transpose W (KxN) -> WT (NxK) with bf16 hi/lo split ----------------
__global__ __launch_bounds__(256) void k_trans_split(const float* __restrict__ src, int N,
                                                     u16* __restrict__ dh, u16* __restrict__ dl,
                                                     int rowOff) {
  __shared__ float t[64][65];
  int n0 = blockIdx.x * 64, k0 = blockIdx.y * 64;
  int tid = threadIdx.x;
  int c = tid & 63, r4 = tid >> 6;
#pragma unroll
  for (int it = 0; it < 16; it++) {
    int kk = it * 4 + r4;
    t[kk][c] = src[(size_t)(k0 + kk) * N + n0 + c];
  }
  __syncthreads();
#pragma unroll
  for (int it = 0; it < 16; it++) {
    int nn = it * 4 + r4;
    float v = t[c][nn];
    u16 hh = f2bf(v);
    size_t o = (size_t)(rowOff + n0 + nn) * 2048 + k0 + c;
    dh[o] = hh;
    dl[o] = f2bf(v - bf2f(hh));
  }
}

// ---------------- transpose wo (KxN fp32) -> woT (NxK f16) ----------------
__global__ __launch_bounds__(256) void k_trans_f16(const float* __restrict__ src, int N,
                                                   u16* __restrict__ dst) {
  __shared__ float t[64][65];
  int n0 = blockIdx.x * 64, k0 = blockIdx.y * 64;
  int tid = threadIdx.x;
  int c = tid & 63, r4 = tid >> 6;
#pragma unroll
  for (int it = 0; it < 16; it++) {
    int kk = it * 4 + r4;
    t[kk][c] = src[(size_t)(k0 + kk) * N + n0 + c];
  }
  __syncthreads();
#pragma unroll
  for (int it = 0; it < 16; it++) {
    int nn = it * 4 + r4;
    dst[(size_t)(n0 + nn) * 2048 + k0 + c] = f2h(t[c][nn]);
  }
}

// ---------------- QKV projection: bf16x3 split GEMM, 128x128 tile, BK=64 ----------------
__global__ __launch_bounds__(256) void k_gemm_qkv(
    const u16* __restrict__ xh, const u16* __restrict__ xl,
    const u16* __restrict__ wth, const u16* __restrict__ wtl,
    float* __restrict__ qkv) {
  __shared__ u16 lds[4 * 128 * 64];  // Ah | Al | Bh | Bl, 64KB
  const int tid = threadIdx.x;
  const int lane = tid & 63, wid = tid >> 6;
  const int rg = lane >> 4, c16 = lane & 15;
  const int m0 = blockIdx.y * 128, n0 = blockIdx.x * 128;
  const int wm = wid >> 1, wn = wid & 1;
  const u16* gsrc = (wid == 0) ? xh + (size_t)m0 * 2048
                  : (wid == 1) ? xl + (size_t)m0 * 2048
                  : (wid == 2) ? wth + (size_t)n0 * 2048
                               : wtl + (size_t)n0 * 2048;
  u16* ldsm = lds + wid * 8192;
  const int sr = lane >> 3, scn = lane & 7;

  f32x4 acc[4][4];
#pragma unroll
  for (int a = 0; a < 4; a++)
#pragma unroll
    for (int b = 0; b < 4; b++) acc[a][b] = (f32x4){0.f, 0.f, 0.f, 0.f};

  for (int k0 = 0; k0 < 2048; k0 += 64) {
#pragma unroll
    for (int i = 0; i < 16; i++) {
      int r = i * 8 + sr;
      int cs = (scn ^ (r & 7)) * 8;  // inverse-swizzled global source (rule #21)
      gll16(gsrc + (size_t)r * 2048 + k0 + cs, ldsm + i * 512);
    }
    __syncthreads();
#pragma unroll
    for (int kk = 0; kk < 2; kk++) {
      short8 ah[4], al[4], bh[4], bl[4];
      int ch = kk * 4 + rg;
#pragma unroll
      for (int mf = 0; mf < 4; mf++) {
        int m = wm * 64 + mf * 16 + c16;
        int off = m * 64 + ((ch ^ (m & 7)) * 8);
        ah[mf] = *(const short8*)(lds + off);
        al[mf] = *(const short8*)(lds + 8192 + off);
      }
#pragma unroll
      for (int nf = 0; nf < 4; nf++) {
        int n = wn * 64 + nf * 16 + c16;
        int off = n * 64 + ((ch ^ (n & 7)) * 8);
        bh[nf] = *(const short8*)(lds + 16384 + off);
        bl[nf] = *(const short8*)(lds + 24576 + off);
      }
#pragma unroll
      for (int mf = 0; mf < 4; mf++)
#pragma unroll
        for (int nf = 0; nf < 4; nf++) {
          acc[mf][nf] = __builtin_amdgcn_mfma_f32_16x16x32_bf16(ah[mf], bh[nf], acc[mf][nf], 0, 0, 0);
          acc[mf][nf] = __builtin_amdgcn_mfma_f32_16x16x32_bf16(ah[mf], bl[nf], acc[mf][nf], 0, 0, 0);
          acc[mf][nf] = __builtin_amdgcn_mfma_f32_16x16x32_bf16(al[mf], bh[nf], acc[mf][nf], 0, 0, 0);
        }
    }
    __syncthreads();
  }
#pragma unroll
  for (int mf = 0; mf < 4; mf++)
#pragma unroll
    for (int nf = 0; nf < 4; nf++)
#pragma unroll
      for (int j = 0; j < 4; j++) {
        int m = m0 + wm * 64 + mf * 16 + rg * 4 + j;
        int n = n0 + wn * 64 + nf * 16 + c16;
        qkv[(size_t)m * QKVN + n] = acc[mf][nf][j];
      }
}

// ---------------- RoPE q,k -> f16 (q pre-scaled by inv_sqrt_d*log2e) ----------------
__global__ __launch_bounds__(256) void k_rope_qk(const float* __restrict__ qkv,
                                                 const float* __restrict__ cosb,
                                                 const float* __restrict__ sinb,
                                                 u16* __restrict__ qf, u16* __restrict__ kf) {
  int idx = blockIdx.x * 256 + threadIdx.x;  // SQ*24*64
  int i = idx & 63;
  int th = idx >> 6;
  int h = th % 24, t = th / 24;
  int c0 = (h < 16) ? h * 128 + 2 * i : 2048 + (h - 16) * 128 + 2 * i;
  float2 eo = *(const float2*)(qkv + (size_t)t * QKVN + c0);
  float c = cosb[t * 64 + i], s = sinb[t * 64 + i];
  float re = eo.x * c - eo.y * s;
  float ro = eo.x * s + eo.y * c;
  if (h < 16) {
    const float QSC = (float)(1.4426950408889634 * 0.08838834764831843);  // log2e/sqrt(128)
    u32 pk = (u32)f2h(re * QSC) | ((u32)f2h(ro * QSC) << 16);
    *(u32*)(qf + ((size_t)h * SQ + t) * 128 + 2 * i) = pk;
  } else {
    u32 pk = (u32)f2h(re) | ((u32)f2h(ro) << 16);
    *(u32*)(kf + ((size_t)(h - 16) * SQ + t) * 128 + 2 * i) = pk;
  }
}

// ---------------- block means of roped k (double accumulation) ----------------
__global__ __launch_bounds__(64) void k_bm(const float* __restrict__ qkv,
                                           const float* __restrict__ cosb,
                                           const float* __restrict__ sinb,
                                           float* __restrict__ bm) {
  int hk = blockIdx.x >> 5, n = blockIdx.x & 31;
  int i = threadIdx.x;  // 64 pairs
  double se = 0.0, so = 0.0;
  for (int t = 0; t < 128; t++) {
    int tt = n * 128 + t;
    float2 eo = *(const float2*)(qkv + (size_t)tt * QKVN + 2048 + hk * 128 + 2 * i);
    float c = cosb[tt * 64 + i], s = sinb[tt * 64 + i];
    se += (double)(eo.x * c - eo.y * s);
    so += (double)(eo.x * s + eo.y * c);
  }
  float* o = bm + ((size_t)(hk * 32 + n)) * 128 + 2 * i;
  o[0] = (float)(se * (1.0 / 128.0));
  o[1] = (float)(so * (1.0 / 128.0));
}

// ---------------- gating: own-block in top-8? (only matters for b>=8) ----------------
__global__ __launch_bounds__(64) void k_gate(const float* __restrict__ qkv,
                                             const float* __restrict__ cosb,
                                             const float* __restrict__ sinb,
                                             const float* __restrict__ bm,
                                             unsigned char* __restrict__ sel) {
  __shared__ float q[64][129];
  __shared__ float bml[32 * 128];
  int bz = blockIdx.x;  // h*48 + (b-8)*2 + half
  int h = bz / 48;
  int rem = bz % 48;
  int b = 8 + (rem >> 1);
  int half = rem & 1;
  int tid = threadIdx.x;
  int hk = h >> 1;
  // cooperative load + rope of the 64 q rows (fp32)
  for (int rr = 0; rr < 64; rr++) {
    int ss = b * 128 + half * 64 + rr;
    float2 eo = *(const float2*)(qkv + (size_t)ss * QKVN + h * 128 + 2 * tid);
    float c = cosb[ss * 64 + tid], sn = sinb[ss * 64 + tid];
    q[rr][2 * tid]     = eo.x * c - eo.y * sn;
    q[rr][2 * tid + 1] = eo.x * sn + eo.y * c;
  }
  for (int o = tid; o < (b + 1) * 128; o += 64) bml[o] = bm[(size_t)hk * 32 * 128 + o];
  __syncthreads();
  int s = b * 128 + half * 64 + tid;
  double gb = 0.0;
  for (int d = 0; d < 128; d++) gb += (double)q[tid][d] * (double)bml[b * 128 + d];
  int cnt = 0;
  for (int n = 0; n < b; n++) {
    double g = 0.0;
    for (int d = 0; d < 128; d++) g += (double)q[tid][d] * (double)bml[n * 128 + d];
    cnt += (g >= gb) ? 1 : 0;
  }
  sel[h * SQ + s] = (cnt <= 7) ? 1 : 0;
}

// ---------------- transpose v -> vt[hk][d][t] f16 ----------------
__global__ __launch_bounds__(256) void k_vt(const float* __restrict__ qkv, u16* __restrict__ vt) {
  __shared__ float t[64][65];
  int hk = blockIdx.z, d0 = blockIdx.y * 64, t0 = blockIdx.x * 64;
  int tid = threadIdx.x;
  int c = tid & 63, r4 = tid >> 6;
#pragma unroll
  for (int it = 0; it < 16; it++) {
    int trow = it * 4 + r4;
    t[trow][c] = qkv[(size_t)(t0 + trow) * QKVN + 3072 + hk * 128 + d0 + c];
  }
  __syncthreads();
#pragma unroll
  for (int it = 0; it < 16; it++) {
    int dd = it * 4 + r4;
    vt[((size_t)hk * 128 + d0 + dd) * SQ + t0 + c] = f2h(t[c][dd]);
  }
}

// ---------------- flash attention over block-dense KV ----------------
__global__ __launch_bounds__(256) void k_attn(
    const u16* __restrict__ qf, const u16* __restrict__ kf, const u16* __restrict__ vt,
    const unsigned char* __restrict__ sel, u16* __restrict__ attn) {
  __shared__ u16 kv[128 * 128];      // 32KB, reused for K then V per tile
  __shared__ u16 pl[4][32 * 128];    // 32KB, per-wave P
  const int h = blockIdx.y, qb = blockIdx.x;
  const int hk = h >> 1;
  const int tid = threadIdx.x;
  const int lane = tid & 63, wid = tid >> 6;
  const int rg = lane >> 4, c16 = lane & 15;
  const int nt = (qb < 8) ? 8 : (qb + 1);
  const bool hasMask = (qb >= 8);

  half8 aq[2][4];
#pragma unroll
  for (int mi = 0; mi < 2; mi++)
#pragma unroll
    for (int kk = 0; kk < 4; kk++) {
      int srow = qb * 128 + wid * 32 + mi * 16 + c16;
      aq[mi][kk] = *(const half8*)(qf + ((size_t)h * SQ + srow) * 128 + kk * 32 + rg * 8);
    }

  f32x4 accO[2][8];
#pragma unroll
  for (int mi = 0; mi < 2; mi++)
#pragma unroll
    for (int nf = 0; nf < 8; nf++) accO[mi][nf] = (f32x4){0.f, 0.f, 0.f, 0.f};
  float mrun[2][4], lrun[2][4];
#pragma unroll
  for (int mi = 0; mi < 2; mi++)
#pragma unroll
    for (int j = 0; j < 4; j++) { mrun[mi][j] = -1e30f; lrun[mi][j] = 0.f; }

  bool os[2][4];
#pragma unroll
  for (int mi = 0; mi < 2; mi++)
#pragma unroll
    for (int j = 0; j < 4; j++) os[mi][j] = true;
  if (hasMask) {
#pragma unroll
    for (int mi = 0; mi < 2; mi++)
#pragma unroll
      for (int j = 0; j < 4; j++)
        os[mi][j] = sel[h * SQ + qb * 128 + wid * 32 + mi * 16 + rg * 4 + j] != 0;
  }

  for (int n = 0; n < nt; n++) {
    // stage K tile [128 tok][128 d]
#pragma unroll
    for (int i = 0; i < 8; i++) {
      int slot = wid * 8 + i;
      int r = slot * 4 + rg;
      int cs = (c16 ^ (r & 7)) * 8;
      gll16(kf + ((size_t)hk * SQ + n * 128 + r) * 128 + cs, kv + slot * 512);
    }
    __syncthreads();

    f32x4 accS[2][8];
#pragma unroll
    for (int mi = 0; mi < 2; mi++)
#pragma unroll
      for (int nf = 0; nf < 8; nf++) accS[mi][nf] = (f32x4){0.f, 0.f, 0.f, 0.f};

#pragma unroll
    for (int kk = 0; kk < 4; kk++) {
      half8 bk[8];
#pragma unroll
      for (int nf = 0; nf < 8; nf++) {
        int t = nf * 16 + c16;
        int ch = kk * 4 + rg;
        bk[nf] = *(const half8*)(kv + t * 128 + ((ch ^ (t & 7)) * 8));
      }
#pragma unroll
      for (int nf = 0; nf < 8; nf++)
#pragma unroll
        for (int mi = 0; mi < 2; mi++)
          accS[mi][nf] = __builtin_amdgcn_mfma_f32_16x16x32_f16(aq[mi][kk], bk[nf], accS[mi][nf], 0, 0, 0);
    }

    if (hasMask && (n == nt - 1)) {
#pragma unroll
      for (int mi = 0; mi < 2; mi++)
#pragma unroll
        for (int j = 0; j < 4; j++) {
          if (!os[mi][j]) {
            int rl = wid * 32 + mi * 16 + rg * 4 + j;
#pragma unroll
            for (int nf = 0; nf < 8; nf++) {
              int tl = nf * 16 + c16;
              if (tl > rl) accS[mi][nf][j] = -1e30f;
            }
          }
        }
    }

    // online softmax (scores already in log2 units)
#pragma unroll
    for (int mi = 0; mi < 2; mi++)
#pragma unroll
      for (int j = 0; j < 4; j++) {
        float mt = accS[mi][0][j];
#pragma unroll
        for (int nf = 1; nf < 8; nf++) mt = fmaxf(mt, accS[mi][nf][j]);
        mt = fmaxf(mt, __shfl_xor(mt, 1, 64));
        mt = fmaxf(mt, __shfl_xor(mt, 2, 64));
        mt = fmaxf(mt, __shfl_xor(mt, 4, 64));
        mt = fmaxf(mt, __shfl_xor(mt, 8, 64));
        float mnew = fmaxf(mrun[mi][j], mt);
        float sc = exp2f(mrun[mi][j] - mnew);
        mrun[mi][j] = mnew;
        float ps = 0.f;
        int rl = mi * 16 + rg * 4 + j;
#pragma unroll
        for (int nf = 0; nf < 8; nf++) {
          float p = exp2f(accS[mi][nf][j] - mnew);
          ps += p;
          int tl = nf * 16 + c16;
          pl[wid][rl * 128 + (((tl >> 3) ^ (rl & 7)) << 3) + (tl & 7)] = f2h(p);
          accO[mi][nf][j] *= sc;
        }
        ps += __shfl_xor(ps, 1, 64);
        ps += __shfl_xor(ps, 2, 64);
        ps += __shfl_xor(ps, 4, 64);
        ps += __shfl_xor(ps, 8, 64);
        lrun[mi][j] = lrun[mi][j] * sc + ps;
      }

    __syncthreads();
    // stage V tile [128 d][128 tok] into same buffer
#pragma unroll
    for (int i = 0; i < 8; i++) {
      int slot = wid * 8 + i;
      int r = slot * 4 + rg;
      int cs = (c16 ^ (r & 7)) * 8;
      gll16(vt + ((size_t)hk * 128 + r) * SQ + n * 128 + cs, kv + slot * 512);
    }
    __syncthreads();

#pragma unroll
    for (int kk = 0; kk < 4; kk++) {
      half8 pa[2];
#pragma unroll
      for (int mi = 0; mi < 2; mi++) {
        int rl = mi * 16 + c16;
        int ch = kk * 4 + rg;
        pa[mi] = *(const half8*)(&pl[wid][rl * 128 + ((ch ^ (rl & 7)) * 8)]);
      }
#pragma unroll
      for (int nf = 0; nf < 8; nf++) {
        int dd = nf * 16 + c16;
        int ch = kk * 4 + rg;
        half8 vb = *(const half8*)(kv + dd * 128 + ((ch ^ (dd & 7)) * 8));
#pragma unroll
        for (int mi = 0; mi < 2; mi++)
          accO[mi][nf] = __builtin_amdgcn_mfma_f32_16x16x32_f16(pa[mi], vb, accO[mi][nf], 0, 0, 0);
      }
    }
    __syncthreads();
  }

#pragma unroll
  for (int mi = 0; mi < 2; mi++)
#pragma unroll
    for (int j = 0; j < 4; j++) {
      float inv = 1.0f / lrun[mi][j];
      int srow = qb * 128 + wid * 32 + mi * 16 + rg * 4 + j;
#pragma unroll
      for (int nf = 0; nf < 8; nf++) {
        int dd = nf * 16 + c16;
        attn[(size_t)srow * DIMM + h * 128 + dd] = f2h(accO[mi][nf][j] * inv);
      }
    }
}

// ---------------- out = attn @ wo (f16 GEMM, fp32 out) ----------------
__global__ __launch_bounds__(256) void k_gemm_out(
    const u16* __restrict__ attn, const u16* __restrict__ wot, float* __restrict__ out) {
  __shared__ u16 lds[2 * 128 * 64];  // A | B, 32KB
  const int tid = threadIdx.x;
  const int lane = tid & 63, wid = tid >> 6;
  const int rg = lane >> 4, c16 = lane & 15;
  const int m0 = blockIdx.y * 128, n0 = blockIdx.x * 128;
  const int wm = wid >> 1, wn = wid & 1;
  const u16* gsrc = (wid < 2) ? attn + (size_t)m0 * 2048 : wot + (size_t)n0 * 2048;
  const int sr = lane >> 3, scn = lane & 7;

  f32x4 acc[4][4];
#pragma unroll
  for (int a = 0; a < 4; a++)
#pragma unroll
    for (int b = 0; b < 4; b++) acc[a][b] = (f32x4){0.f, 0.f, 0.f, 0.f};

  for (int k0 = 0; k0 < 2048; k0 += 64) {
#pragma unroll
    for (int i = 0; i < 8; i++) {
      int slot = wid * 8 + i;
      int s2 = slot & 15;
      int r = s2 * 8 + sr;
      int cs = (scn ^ (r & 7)) * 8;
      gll16(gsrc + (size_t)r * 2048 + k0 + cs, lds + slot * 512);
    }
    __syncthreads();
#pragma unroll
    for (int kk = 0; kk < 2; kk++) {
      half8 a[4], b[4];
      int ch = kk * 4 + rg;
#pragma unroll
      for (int mf = 0; mf < 4; mf++) {
        int m = wm * 64 + mf * 16 + c16;
        a[mf] = *(const half8*)(lds + m * 64 + ((ch ^ (m & 7)) * 8));
      }
#pragma unroll
      for (int nf = 0; nf < 4; nf++) {
        int n = wn * 64 + nf * 16 + c16;
        b[nf] = *(const half8*)(lds + 8192 + n * 64 + ((ch ^ (n & 7)) * 8));
      }
#pragma unroll
      for (int mf = 0; mf < 4; mf++)
#pragma unroll
        for (int nf = 0; nf < 4; nf++)
          acc[mf][nf] = __builtin_amdgcn_mfma_f32_16x16x32_f16(a[mf], b[nf], acc[mf][nf], 0, 0, 0);
    }
    __syncthreads();
  }
#pragma unroll
  for (int mf = 0; mf < 4; mf++)
#pragma unroll
    for (int nf = 0; nf < 4; nf++)
#pragma unroll
      for (int j = 0; j < 4; j++) {
        int m = m0 + wm * 64 + mf * 16 + rg * 4 + j;
        int n = n0 + wn * 64 + nf * 16 + c16;
        out[(size_t)m * DIMM + n] = acc[mf][nf][j];
      }
}

extern "C" void kernel_launch(void* const* d_in, const int* in_sizes, int n_in,
                              void* d_out, int out_size, void* d_ws, size_t ws_size,
                              hipStream_t stream) {
  (void)in_sizes; (void)n_in; (void)out_size; (void)ws_size;
  const float* x  = (const float*)d_in[0];
  const float* wq = (const float*)d_in[1];
  const float* wk = (const float*)d_in[2];
  const float* wv = (const float*)d_in[3];
  const float* wo = (const float*)d_in[4];
  float* out = (float*)d_out;

  char* ws = (char*)d_ws;
  size_t off = 0;
  auto alloc = [&](size_t b) { char* p = ws + off; off += (b + 255) & ~(size_t)255; return p; };

  u16*   xh   = (u16*)alloc((size_t)SQ * DIMM * 2);
  u16*   xl   = (u16*)alloc((size_t)SQ * DIMM * 2);
  u16*   wth  = (u16*)alloc((size_t)QKVN * DIMM * 2);
  u16*   wtl  = (u16*)alloc((size_t)QKVN * DIMM * 2);
  u16*   wot  = (u16*)alloc((size_t)DIMM * DIMM * 2);
  float* qkv  = (float*)alloc((size_t)SQ * QKVN * 4);
  float* cosb = (float*)alloc((size_t)SQ * 64 * 4);
  float* sinb = (float*)alloc((size_t)SQ * 64 * 4);
  u16*   qf   = (u16*)alloc((size_t)16 * SQ * 128 * 2);
  u16*   kf   = (u16*)alloc((size_t)8 * SQ * 128 * 2);
  u16*   vt   = (u16*)alloc((size_t)8 * 128 * SQ * 2);
  float* bm   = (float*)alloc((size_t)8 * 32 * 128 * 4);
  unsigned char* sel = (unsigned char*)alloc((size_t)16 * SQ);
  u16*   attn = (u16*)alloc((size_t)SQ * DIMM * 2);

  k_tables<<<SQ * 64 / 256, 256, 0, stream>>>(cosb, sinb);
  k_split_x<<<(SQ * DIMM) / (256 * 4), 256, 0, stream>>>(x, xh, xl);
  k_trans_split<<<dim3(32, 32), 256, 0, stream>>>(wq, 2048, wth, wtl, 0);
  k_trans_split<<<dim3(16, 32), 256, 0, stream>>>(wk, 1024, wth, wtl, 2048);
  k_trans_split<<<dim3(16, 32), 256, 0, stream>>>(wv, 1024, wth, wtl, 3072);
  k_trans_f16<<<dim3(32, 32), 256, 0, stream>>>(wo, 2048, wot);
  k_gemm_qkv<<<dim3(32, 32), 256, 0, stream>>>(xh, xl, wth, wtl, qkv);
  k_rope_qk<<<(SQ * 24 * 64) / 256, 256, 0, stream>>>(qkv, cosb, sinb, qf, kf);
  k_vt<<<dim3(64, 2, 8), 256, 0, stream>>>(qkv, vt);
  k_bm<<<256, 64, 0, stream>>>(qkv, cosb, sinb, bm);
  k_gate<<<16 * 48, 64, 0, stream>>>(qkv, cosb, sinb, bm, sel);
  k_attn<<<dim3(32, 16), 256, 0, stream>>>(qf, kf, vt, sel, attn);
  k_gemm_out<<<dim3(16, 32), 256, 0, stream>>>(attn, wot, out);
}